// Round 3
// baseline (480.052 us; speedup 1.0000x reference)
//
#include <hip/hip_runtime.h>
#include <hip/hip_bf16.h>

// WindowAttention fused kernel v6 (MI355X / gfx950)
// One block = one window. 4 waves, wave = head everywhere.
// v6 changes vs v3 (current best, 321us):
//  - phase 1 is tt-OUTER: xa[4] (16 regs) loaded+converted ONCE per token tile,
//    all 6 weight tiles consumed against it. v3's xa[4][4] (64 regs) forced the
//    allocator to remat x from GLOBAL + reconvert 6x (VGPR=64 tell, VALU 28.6%).
//    Redundant cost moved to wf reloads: bf16, L2-hot, no converts.
//  - phases 2+3 merged per q-tile nt: P^T lives as pkn[4][2] (8 regs) inside
//    one iteration instead of persistent pk[4][4][2] (32 regs). Barrier sits
//    after kb-load/va-build (all waves hold K in regs before any O store).
//  - v5 lesson: persistent arrays pkQ/pkK/pk together spill (VGPR=48, FETCH 3.4x).
//    Here persistent state is only pkV (16) -> demand ~90 under the 128 cap.
//  - LDS 32KB (Q 16K @0; K 16K @16384, O aliases K), launch_bounds(256,4).

#define T49  49
#define CDIM 128
#define NW   64
#define SCALEF 0.17677669529663689f   // 1/sqrt(32)

typedef short bf16x8 __attribute__((ext_vector_type(8)));
typedef float f32x4  __attribute__((ext_vector_type(4)));

union B8 { unsigned int u[4]; bf16x8 v; };

__device__ __forceinline__ unsigned int pk2(float a, float b) {
  __hip_bfloat162 h = __float22bfloat162_rn(make_float2(a, b));
  unsigned int u;
  __builtin_memcpy(&u, &h, 4);
  return u;
}

__device__ __forceinline__ unsigned short f2bf(float f) {
  unsigned int u = __builtin_bit_cast(unsigned int, f);
  u += 0x7fffu + ((u >> 16) & 1u);
  return (unsigned short)(u >> 16);
}

// prep: bf16 weights + padded mask maskp[64][64 q][64 key], pads = -1e30
__global__ void prep_kernel(const float* __restrict__ wq, const float* __restrict__ wp,
                            const float* __restrict__ mask,
                            short* __restrict__ wq_bf, short* __restrict__ wp_bf,
                            float* __restrict__ maskp) {
  const int i = blockIdx.x * 256 + threadIdx.x;      // grid covers 262144
  const int w = i >> 12, q = (i >> 6) & 63, k = i & 63;
  float mv = -1e30f;
  if (q < T49 && k < T49) mv = mask[(w * T49 + q) * T49 + k];
  maskp[i] = mv;
  if (i < 3 * CDIM * CDIM) wq_bf[i] = (short)f2bf(wq[i]);
  if (i < CDIM * CDIM)     wp_bf[i] = (short)f2bf(wp[i]);
}

__global__ __launch_bounds__(256, 4)
void winattn_kernel(const float* __restrict__ x, const float* __restrict__ maskp,
                    const float* __restrict__ b_qkv, const float* __restrict__ b_proj,
                    const short* __restrict__ wq, const short* __restrict__ wp,
                    float* __restrict__ out) {
  // LDS (32 KB -> 4 blocks/CU):
  //  Q  [4h][64 t][32 d] bf16 @ 0      (16 KB) swz: dbyte ^ ((t&3)<<4)
  //  K  [4h][64 t][32 d] bf16 @ 16384  (16 KB) same swz; aliased by O after barrier
  //  O  [64 t][128 ch]   bf16 @ 16384  (16 KB) swz: chbyte ^ ((t&7)<<5)
  //  V: registers only (pkV)
  __shared__ __align__(16) char smem[32768];
  constexpr int Q_BASE = 0, KO_BASE = 16384;

  const int bw    = blockIdx.x;
  const int wv    = threadIdx.x >> 6;
  const int lane  = threadIdx.x & 63;
  const int g     = lane >> 4;
  const int j16   = lane & 15;
  const int wmask = bw & (NW - 1);

  // ---------------- bias prefetch (hoisted out of the tt loop) ----------------
  float4 bQK[4];
#pragma unroll
  for (int ni = 0; ni < 4; ++ni) {
    const int ct = (ni < 2) ? (wv * 2 + ni) : (8 + wv * 2 + (ni - 2));
    bQK[ni] = *(const float4*)(b_qkv + ct * 16 + g * 4);
  }
  float bV[2];
#pragma unroll
  for (int vi = 0; vi < 2; ++vi)
    bV[vi] = b_qkv[(16 + wv * 2 + vi) * 16 + j16];

  // ---------------- Phase 1: QKV, tt-outer (wave wv = head wv) ----------------
  unsigned int pkV[2][4][2];  // [d-tile vi][tt][pair]: pairs along token (natural D[t][c])
  const float* xb = x + (size_t)bw * (T49 * CDIM);

#pragma unroll
  for (int tt = 0; tt < 4; ++tt) {
    const int t = tt * 16 + j16;
    bf16x8 xa[4];             // x fragments for THIS token tile only (16 regs)
#pragma unroll
    for (int kt = 0; kt < 4; ++kt) {
      B8 u;
      if (t < T49) {
        const float* p = xb + t * CDIM + kt * 32 + g * 8;
        const float4 v0 = *(const float4*)p;
        const float4 v1 = *(const float4*)(p + 4);
        u.u[0] = pk2(v0.x, v0.y); u.u[1] = pk2(v0.z, v0.w);
        u.u[2] = pk2(v1.x, v1.y); u.u[3] = pk2(v1.z, v1.w);
      } else {
        u.u[0] = u.u[1] = u.u[2] = u.u[3] = 0u;
      }
      xa[kt] = u.v;
    }
#pragma unroll
    for (int ni = 0; ni < 6; ++ni) {
      const int ct = (ni < 2) ? (wv * 2 + ni)
                   : (ni < 4) ? (8 + wv * 2 + (ni - 2))
                              : (16 + wv * 2 + (ni - 4));
      bf16x8 wf[4];           // w frag: row c=ct*16+j16, k=kt*32+g*8..+7
#pragma unroll
      for (int kt = 0; kt < 4; ++kt)
        wf[kt] = *(const bf16x8*)(wq + (ct * 16 + j16) * CDIM + kt * 32 + g * 8);

      if (ni < 4) {
        // swapped: D[c][t]; lane holds 4 consecutive channels at token t
        f32x4 acc = {0.f, 0.f, 0.f, 0.f};
#pragma unroll
        for (int kt = 0; kt < 4; ++kt)
          acc = __builtin_amdgcn_mfma_f32_16x16x32_bf16(wf[kt], xa[kt], acc, 0, 0, 0);
        const bool  isQ = (ni < 2);
        const float sc  = isQ ? SCALEF : 1.0f;
        const float4 b4 = bQK[ni];
        const int   d0  = (ct * 16 + g * 4) & 31;
        char* base = smem + (isQ ? Q_BASE : KO_BASE) + wv * 4096;
        const uint2 w2 = make_uint2(pk2(fmaf(acc[0], sc, b4.x * sc), fmaf(acc[1], sc, b4.y * sc)),
                                    pk2(fmaf(acc[2], sc, b4.z * sc), fmaf(acc[3], sc, b4.w * sc)));
        *(uint2*)(base + t * 64 + ((d0 * 2) ^ ((t & 3) << 4))) = w2;
      } else {
        // V natural: D[t][c] -> registers (pairs along token)
        f32x4 acc = {0.f, 0.f, 0.f, 0.f};
#pragma unroll
        for (int kt = 0; kt < 4; ++kt)
          acc = __builtin_amdgcn_mfma_f32_16x16x32_bf16(xa[kt], wf[kt], acc, 0, 0, 0);
        const int vi = ni - 4;
        pkV[vi][tt][0] = pk2(acc[0] + bV[vi], acc[1] + bV[vi]);
        pkV[vi][tt][1] = pk2(acc[2] + bV[vi], acc[3] + bV[vi]);
      }
    }
  }
  // NO barrier yet: kb loads below read only this wave's own K writes.

  // ---------------- Phase 2 prologue: kb from LDS, va from pkV ----------------
  const int gh   = g >> 1;
  const int srcA = (((2 * g    ) & 3) << 4) | j16;
  const int srcB = (((2 * g + 1) & 3) << 4) | j16;

  const char* Kb = smem + KO_BASE + wv * 4096;
  bf16x8 kb[4];
#pragma unroll
  for (int mt = 0; mt < 4; ++mt) {
    const int t = mt * 16 + j16;
    kb[mt] = *(const bf16x8*)(Kb + t * 64 + ((g * 16) ^ ((t & 3) << 4)));
  }

  // va[dt][ks] elem e wants V[key=ks*32+8g+e][d=dt*16+j16]: source tile
  // tt = 2ks + (g>>1), lane (2g+(e>>2))&3 group, pair (e&3)>>1.
  bf16x8 va[2][2];
#pragma unroll
  for (int dt = 0; dt < 2; ++dt)
#pragma unroll
    for (int ks = 0; ks < 2; ++ks) {
      const unsigned int a0  = (unsigned)__shfl((int)pkV[dt][2 * ks    ][0], srcA, 64);
      const unsigned int a0h = (unsigned)__shfl((int)pkV[dt][2 * ks + 1][0], srcA, 64);
      const unsigned int a1  = (unsigned)__shfl((int)pkV[dt][2 * ks    ][1], srcA, 64);
      const unsigned int a1h = (unsigned)__shfl((int)pkV[dt][2 * ks + 1][1], srcA, 64);
      const unsigned int b0  = (unsigned)__shfl((int)pkV[dt][2 * ks    ][0], srcB, 64);
      const unsigned int b0h = (unsigned)__shfl((int)pkV[dt][2 * ks + 1][0], srcB, 64);
      const unsigned int b1  = (unsigned)__shfl((int)pkV[dt][2 * ks    ][1], srcB, 64);
      const unsigned int b1h = (unsigned)__shfl((int)pkV[dt][2 * ks + 1][1], srcB, 64);
      B8 u;
      u.u[0] = gh ? a0h : a0;
      u.u[1] = gh ? a1h : a1;
      u.u[2] = gh ? b0h : b0;
      u.u[3] = gh ? b1h : b1;
      va[dt][ks] = u.v;
    }

  __syncthreads();   // every wave's kb is in registers -> O may overwrite K region

  // ---------------- Phases 2+3 merged, per q-tile nt (wave = head) ----------------
  const char* Qb  = smem + Q_BASE + wv * 4096;
  char*       Ob  = smem + KO_BASE;
  const float* mwb = maskp + wmask * 4096;

#pragma unroll
  for (int nt = 0; nt < 4; ++nt) {
    const int q = nt * 16 + j16;
    const bf16x8 qb = *(const bf16x8*)(Qb + q * 64 + ((g * 16) ^ ((q & 3) << 4)));
    const float* mp = mwb + q * 64 + g * 4;
    float4 m4[4];
#pragma unroll
    for (int mt = 0; mt < 4; ++mt) m4[mt] = *(const float4*)(mp + mt * 16);

    const f32x4 zero = {0.f, 0.f, 0.f, 0.f};
    float v[4][4];
#pragma unroll
    for (int mt = 0; mt < 4; ++mt) {
      const f32x4 s = __builtin_amdgcn_mfma_f32_16x16x32_bf16(kb[mt], qb, zero, 0, 0, 0);
      v[mt][0] = s[0] + m4[mt].x; v[mt][1] = s[1] + m4[mt].y;
      v[mt][2] = s[2] + m4[mt].z; v[mt][3] = s[3] + m4[mt].w;
    }
    // depth-4 max tree
    float mr[8];
#pragma unroll
    for (int mt = 0; mt < 4; ++mt) {
      mr[2 * mt]     = fmaxf(v[mt][0], v[mt][1]);
      mr[2 * mt + 1] = fmaxf(v[mt][2], v[mt][3]);
    }
    float mx = fmaxf(fmaxf(fmaxf(mr[0], mr[1]), fmaxf(mr[2], mr[3])),
                     fmaxf(fmaxf(mr[4], mr[5]), fmaxf(mr[6], mr[7])));
    mx = fmaxf(mx, __shfl_xor(mx, 16, 64));
    mx = fmaxf(mx, __shfl_xor(mx, 32, 64));
    // exp + depth-4 sum tree
    float sr[8];
#pragma unroll
    for (int mt = 0; mt < 4; ++mt) {
      v[mt][0] = __expf(v[mt][0] - mx); v[mt][1] = __expf(v[mt][1] - mx);
      v[mt][2] = __expf(v[mt][2] - mx); v[mt][3] = __expf(v[mt][3] - mx);
      sr[2 * mt]     = v[mt][0] + v[mt][1];
      sr[2 * mt + 1] = v[mt][2] + v[mt][3];
    }
    float sum = ((sr[0] + sr[1]) + (sr[2] + sr[3])) + ((sr[4] + sr[5]) + (sr[6] + sr[7]));
    sum += __shfl_xor(sum, 16, 64);
    sum += __shfl_xor(sum, 32, 64);
    const float inv = 1.0f / sum;

    // P^T for THIS nt only: pairs along key (8 regs, per-iteration live range)
    unsigned int pkn[4][2];
#pragma unroll
    for (int mt = 0; mt < 4; ++mt) {
      pkn[mt][0] = pk2(v[mt][0] * inv, v[mt][1] * inv);
      pkn[mt][1] = pk2(v[mt][2] * inv, v[mt][3] * inv);
    }

    // redistribute P^T + PV MFMAs
    f32x4 oacc[2] = {{0.f,0.f,0.f,0.f},{0.f,0.f,0.f,0.f}};
#pragma unroll
    for (int ks = 0; ks < 2; ++ks) {
      const unsigned int p00 = (unsigned)__shfl((int)pkn[2*ks  ][0], srcA, 64);
      const unsigned int p10 = (unsigned)__shfl((int)pkn[2*ks+1][0], srcA, 64);
      const unsigned int p01 = (unsigned)__shfl((int)pkn[2*ks  ][1], srcA, 64);
      const unsigned int p11 = (unsigned)__shfl((int)pkn[2*ks+1][1], srcA, 64);
      const unsigned int q00 = (unsigned)__shfl((int)pkn[2*ks  ][0], srcB, 64);
      const unsigned int q10 = (unsigned)__shfl((int)pkn[2*ks+1][0], srcB, 64);
      const unsigned int q01 = (unsigned)__shfl((int)pkn[2*ks  ][1], srcB, 64);
      const unsigned int q11 = (unsigned)__shfl((int)pkn[2*ks+1][1], srcB, 64);
      B8 bf;
      bf.u[0] = gh ? p10 : p00;
      bf.u[1] = gh ? p11 : p01;
      bf.u[2] = gh ? q10 : q00;
      bf.u[3] = gh ? q11 : q01;
#pragma unroll
      for (int dt = 0; dt < 2; ++dt)
        oacc[dt] = __builtin_amdgcn_mfma_f32_16x16x32_bf16(va[dt][ks], bf.v, oacc[dt], 0, 0, 0);
    }

    // D[d][q]: 4 regs = consecutive channels -> b64 store into O[t][ch]
    const int to = nt * 16 + j16;
    const int sw = (to & 7) << 5;
#pragma unroll
    for (int dt = 0; dt < 2; ++dt) {
      const int ch0 = wv * 32 + dt * 16 + g * 4;
      const uint2 w2 = make_uint2(pk2(oacc[dt][0], oacc[dt][1]),
                                  pk2(oacc[dt][2], oacc[dt][3]));
      *(uint2*)(Ob + to * 256 + ((ch0 * 2) ^ sw)) = w2;
    }
  }
  __syncthreads();

  // ---------------- Phase 4: out = O @ wp^T + b ----------------
  {
    const char* Ob = smem + KO_BASE;
    bf16x8 oa[4][4];
#pragma unroll
    for (int mt = 0; mt < 4; ++mt) {
      const int t = mt * 16 + j16;
      const int sw = (t & 7) << 5;
#pragma unroll
      for (int kt = 0; kt < 4; ++kt)
        oa[mt][kt] = *(const bf16x8*)(Ob + t * 256 + ((kt * 64 + g * 16) ^ sw));
    }
    float* ob = out + (size_t)bw * (T49 * CDIM);
#pragma unroll
    for (int ntl = 0; ntl < 2; ++ntl) {
      const int c = (wv * 2 + ntl) * 16 + j16;
      bf16x8 bfr[4];
#pragma unroll
      for (int kt = 0; kt < 4; ++kt)
        bfr[kt] = *(const bf16x8*)(wp + c * CDIM + kt * 32 + g * 8);
      const float bias = b_proj[c];
#pragma unroll
      for (int mt = 0; mt < 4; ++mt) {
        f32x4 acc = {0.f, 0.f, 0.f, 0.f};
#pragma unroll
        for (int kt = 0; kt < 4; ++kt)
          acc = __builtin_amdgcn_mfma_f32_16x16x32_bf16(oa[mt][kt], bfr[kt], acc, 0, 0, 0);
#pragma unroll
        for (int r = 0; r < 4; ++r) {
          const int t = mt * 16 + g * 4 + r;
          if (t < T49) ob[t * CDIM + c] = acc[r] + bias;
        }
      }
    }
  }
}

extern "C" void kernel_launch(void* const* d_in, const int* in_sizes, int n_in,
                              void* d_out, int out_size, void* d_ws, size_t ws_size,
                              hipStream_t stream) {
  const float* x      = (const float*)d_in[0];
  const float* mask   = (const float*)d_in[1];
  const float* w_qkv  = (const float*)d_in[2];
  const float* b_qkv  = (const float*)d_in[3];
  const float* w_proj = (const float*)d_in[4];
  const float* b_proj = (const float*)d_in[5];
  float* out = (float*)d_out;

  float* maskp = (float*)d_ws;                       // 64*64*64 f32 = 1 MB
  short* wq_bf = (short*)((char*)d_ws + 64*64*64*4); // 96 KB
  short* wp_bf = wq_bf + 3 * CDIM * CDIM;            // 32 KB

  hipLaunchKernelGGL(prep_kernel, dim3(1024), dim3(256), 0, stream,
                     w_qkv, w_proj, mask, wq_bf, wp_bf, maskp);
  hipLaunchKernelGGL(winattn_kernel, dim3(8192), dim3(256), 0, stream,
                     x, maskp, b_qkv, b_proj, wq_bf, wp_bf, out);
}

// Round 4
// 295.057 us; speedup vs baseline: 1.6270x; 1.6270x over previous
//
#include <hip/hip_runtime.h>
#include <hip/hip_bf16.h>

// WindowAttention fused kernel v7 (MI355X / gfx950)
// One block = one window. 4 waves, wave = head everywhere.
// v7 = v3 (best, 321us) + serial-chain surgery in ph2/3:
//  - prep pre-shifts mask by per-row max (softmax shift-invariance, EXACT):
//    runtime max pass deleted (15 fmax + 2 shfl_xor x 4nt serial cycles gone)
//  - normalization deferred to oacc: sum/shfl/rcp chain overlaps P-redistribute
//    + PV MFMAs instead of preceding them; inv applied as 8 mults on oacc
//  - ph2+3 merged per q-tile (P: 8 regs transient, no persistent pk[32])
//  - qb[4]+kb[4] preloaded before barrier -> merged loop has no LDS reads
//  - ph1 byte-identical to v3 (ni-outer, batched loads; v6 lesson: never put
//    a fresh global load in front of each MFMA chain)

#define T49  49
#define CDIM 128
#define NW   64
#define SCALEF 0.17677669529663689f   // 1/sqrt(32)

typedef short bf16x8 __attribute__((ext_vector_type(8)));
typedef float f32x4  __attribute__((ext_vector_type(4)));

union B8 { unsigned int u[4]; bf16x8 v; };

__device__ __forceinline__ unsigned int pk2(float a, float b) {
  __hip_bfloat162 h = __float22bfloat162_rn(make_float2(a, b));
  unsigned int u;
  __builtin_memcpy(&u, &h, 4);
  return u;
}

__device__ __forceinline__ unsigned short f2bf(float f) {
  unsigned int u = __builtin_bit_cast(unsigned int, f);
  u += 0x7fffu + ((u >> 16) & 1u);
  return (unsigned short)(u >> 16);
}

// prep: bf16 weights + padded mask maskp[64][64 q][64 key]
//   maskp[w][q][k] = mask - rowmax(mask)  (q<49,k<49)
//                  = -1e30                (q<49,k>=49)  -> exp()=0 exactly
//                  = 0                    (q>=49)       -> finite garbage, unused
__global__ void prep_kernel(const float* __restrict__ wq, const float* __restrict__ wp,
                            const float* __restrict__ mask,
                            short* __restrict__ wq_bf, short* __restrict__ wp_bf,
                            float* __restrict__ maskp) {
  const int i = blockIdx.x * 256 + threadIdx.x;      // grid covers 262144
  const int w = i >> 12, q = (i >> 6) & 63, k = i & 63;
  // one wave == one (w,q) row, lane == k  (256 % 64 == 0)
  float val = -3.0e38f;
  if (q < T49 && k < T49) val = mask[(w * T49 + q) * T49 + k];
  float rm = val;
  rm = fmaxf(rm, __shfl_xor(rm, 1, 64));
  rm = fmaxf(rm, __shfl_xor(rm, 2, 64));
  rm = fmaxf(rm, __shfl_xor(rm, 4, 64));
  rm = fmaxf(rm, __shfl_xor(rm, 8, 64));
  rm = fmaxf(rm, __shfl_xor(rm, 16, 64));
  rm = fmaxf(rm, __shfl_xor(rm, 32, 64));
  float mv;
  if (q >= T49)      mv = 0.0f;
  else if (k >= T49) mv = -1e30f;
  else               mv = val - rm;
  maskp[i] = mv;
  if (i < 3 * CDIM * CDIM) wq_bf[i] = (short)f2bf(wq[i]);
  if (i < CDIM * CDIM)     wp_bf[i] = (short)f2bf(wp[i]);
}

__global__ __launch_bounds__(256, 4)
void winattn_kernel(const float* __restrict__ x, const float* __restrict__ maskp,
                    const float* __restrict__ b_qkv, const float* __restrict__ b_proj,
                    const short* __restrict__ wq, const short* __restrict__ wp,
                    float* __restrict__ out) {
  // LDS (32 KB):
  //  Q  [4h][64 t][32 d] bf16 @ 0      (16 KB) swz: dbyte ^ ((t&3)<<4)
  //  K  [4h][64 t][32 d] bf16 @ 16384  (16 KB) same swz; aliased by O after barrier
  //  O  [64 t][128 ch]   bf16 @ 16384  (16 KB) swz: chbyte ^ ((t&7)<<5)
  //  V: registers only (pkV)
  __shared__ __align__(16) char smem[32768];
  constexpr int Q_BASE = 0, KO_BASE = 16384;

  const int bw    = blockIdx.x;
  const int wv    = threadIdx.x >> 6;
  const int lane  = threadIdx.x & 63;
  const int g     = lane >> 4;
  const int j16   = lane & 15;
  const int wmask = bw & (NW - 1);

  // ---------------- Phase 1: QKV (per-head ownership; identical to v3) ----------------
  bf16x8 xa[4][4];
#pragma unroll
  for (int tt = 0; tt < 4; ++tt) {
    const int t = tt * 16 + j16;
#pragma unroll
    for (int kt = 0; kt < 4; ++kt) {
      B8 u;
      if (t < T49) {
        const float* p = x + (size_t)bw * (T49 * CDIM) + t * CDIM + kt * 32 + g * 8;
        const float4 v0 = *(const float4*)p;
        const float4 v1 = *(const float4*)(p + 4);
        u.u[0] = pk2(v0.x, v0.y); u.u[1] = pk2(v0.z, v0.w);
        u.u[2] = pk2(v1.x, v1.y); u.u[3] = pk2(v1.z, v1.w);
      } else {
        u.u[0] = u.u[1] = u.u[2] = u.u[3] = 0u;
      }
      xa[tt][kt] = u.v;
    }
  }

  unsigned int pkV[2][4][2];  // [d-tile vi][tt][pair]: pairs along token (natural D[t][c])

#pragma unroll
  for (int ni = 0; ni < 6; ++ni) {
    const int ct = (ni < 2) ? (wv * 2 + ni)
                 : (ni < 4) ? (8 + wv * 2 + (ni - 2))
                            : (16 + wv * 2 + (ni - 4));
    bf16x8 wf[4];                                     // w frag: row c=ct*16+j16, k=kt*32+g*8..+7
#pragma unroll
    for (int kt = 0; kt < 4; ++kt)
      wf[kt] = *(const bf16x8*)(wq + (ct * 16 + j16) * CDIM + kt * 32 + g * 8);

    if (ni < 4) {
      // swapped: D[c][t]; 4 regs = consecutive channels -> b64 store into [t][d]
      const int  c0  = ct * 16 + g * 4;
      const bool isQ = (ni < 2);
      float4 b4 = *(const float4*)(b_qkv + c0);
      const float sc = isQ ? SCALEF : 1.0f;           // fold q-scale into Q
      const int d0 = c0 & 31;
      char* base = smem + (isQ ? Q_BASE : KO_BASE) + wv * 4096;
#pragma unroll
      for (int tt = 0; tt < 4; ++tt) {
        f32x4 acc = {0.f, 0.f, 0.f, 0.f};
#pragma unroll
        for (int kt = 0; kt < 4; ++kt)
          acc = __builtin_amdgcn_mfma_f32_16x16x32_bf16(wf[kt], xa[tt][kt], acc, 0, 0, 0);
        const int t = tt * 16 + j16;
        const uint2 w2 = make_uint2(pk2(fmaf(acc[0], sc, b4.x * sc), fmaf(acc[1], sc, b4.y * sc)),
                                    pk2(fmaf(acc[2], sc, b4.z * sc), fmaf(acc[3], sc, b4.w * sc)));
        *(uint2*)(base + t * 64 + ((d0 * 2) ^ ((t & 3) << 4))) = w2;
      }
    } else {
      // V natural: D[t][c] -> registers (pairs along token)
      const int   vi   = ni - 4;
      const float bias = b_qkv[ct * 16 + j16];
#pragma unroll
      for (int tt = 0; tt < 4; ++tt) {
        f32x4 acc = {0.f, 0.f, 0.f, 0.f};
#pragma unroll
        for (int kt = 0; kt < 4; ++kt)
          acc = __builtin_amdgcn_mfma_f32_16x16x32_bf16(xa[tt][kt], wf[kt], acc, 0, 0, 0);
        pkV[vi][tt][0] = pk2(acc[0] + bias, acc[1] + bias);
        pkV[vi][tt][1] = pk2(acc[2] + bias, acc[3] + bias);
      }
    }
  }
  // NO barrier: kb/qb loads below read only this wave's own writes.

  // ---------------- Prologue: kb, qb from own LDS; va from pkV ----------------
  const int gh   = g >> 1;
  const int srcA = (((2 * g    ) & 3) << 4) | j16;
  const int srcB = (((2 * g + 1) & 3) << 4) | j16;

  const char* Kb = smem + KO_BASE + wv * 4096;
  const char* Qb = smem + Q_BASE  + wv * 4096;
  bf16x8 kb[4], qb[4];
#pragma unroll
  for (int mt = 0; mt < 4; ++mt) {
    const int t = mt * 16 + j16;
    kb[mt] = *(const bf16x8*)(Kb + t * 64 + ((g * 16) ^ ((t & 3) << 4)));
    qb[mt] = *(const bf16x8*)(Qb + t * 64 + ((g * 16) ^ ((t & 3) << 4)));
  }

  // va[dt][ks] elem e wants V[key=ks*32+8g+e][d=dt*16+j16]: source tile
  // tt = 2ks + (g>>1), lane (2g+(e>>2))&3 group, pair (e&3)>>1.
  bf16x8 va[2][2];
#pragma unroll
  for (int dt = 0; dt < 2; ++dt)
#pragma unroll
    for (int ks = 0; ks < 2; ++ks) {
      const unsigned int a0  = (unsigned)__shfl((int)pkV[dt][2 * ks    ][0], srcA, 64);
      const unsigned int a0h = (unsigned)__shfl((int)pkV[dt][2 * ks + 1][0], srcA, 64);
      const unsigned int a1  = (unsigned)__shfl((int)pkV[dt][2 * ks    ][1], srcA, 64);
      const unsigned int a1h = (unsigned)__shfl((int)pkV[dt][2 * ks + 1][1], srcA, 64);
      const unsigned int b0  = (unsigned)__shfl((int)pkV[dt][2 * ks    ][0], srcB, 64);
      const unsigned int b0h = (unsigned)__shfl((int)pkV[dt][2 * ks + 1][0], srcB, 64);
      const unsigned int b1  = (unsigned)__shfl((int)pkV[dt][2 * ks    ][1], srcB, 64);
      const unsigned int b1h = (unsigned)__shfl((int)pkV[dt][2 * ks + 1][1], srcB, 64);
      B8 u;
      u.u[0] = gh ? a0h : a0;
      u.u[1] = gh ? a1h : a1;
      u.u[2] = gh ? b0h : b0;
      u.u[3] = gh ? b1h : b1;
      va[dt][ks] = u.v;
    }

  __syncthreads();   // all Q/K reads done in-registers -> O may overwrite K region

  // ---------------- Phases 2+3 merged, per q-tile nt (wave = head) ----------------
  char*        Ob  = smem + KO_BASE;
  const float* mwb = maskp + wmask * 4096;

#pragma unroll
  for (int nt = 0; nt < 4; ++nt) {
    const float* mp = mwb + (nt * 16 + j16) * 64 + g * 4;
    float4 m4[4];
#pragma unroll
    for (int mt = 0; mt < 4; ++mt) m4[mt] = *(const float4*)(mp + mt * 16);

    const f32x4 zero = {0.f, 0.f, 0.f, 0.f};
    float v[4][4];
#pragma unroll
    for (int mt = 0; mt < 4; ++mt) {
      const f32x4 s = __builtin_amdgcn_mfma_f32_16x16x32_bf16(kb[mt], qb[nt], zero, 0, 0, 0);
      // mask is pre-shifted by row max: exp directly, no max pass
      v[mt][0] = __expf(s[0] + m4[mt].x); v[mt][1] = __expf(s[1] + m4[mt].y);
      v[mt][2] = __expf(s[2] + m4[mt].z); v[mt][3] = __expf(s[3] + m4[mt].w);
    }
    // denominator chain (runs in parallel with P-redistribute + PV below)
    float sr[8];
#pragma unroll
    for (int mt = 0; mt < 4; ++mt) {
      sr[2 * mt]     = v[mt][0] + v[mt][1];
      sr[2 * mt + 1] = v[mt][2] + v[mt][3];
    }
    float sum = ((sr[0] + sr[1]) + (sr[2] + sr[3])) + ((sr[4] + sr[5]) + (sr[6] + sr[7]));
    sum += __shfl_xor(sum, 16, 64);
    sum += __shfl_xor(sum, 32, 64);
    const float inv = 1.0f / sum;

    // P^T raw (unnormalized): pairs along key, 8 regs
    unsigned int pkn[4][2];
#pragma unroll
    for (int mt = 0; mt < 4; ++mt) {
      pkn[mt][0] = pk2(v[mt][0], v[mt][1]);
      pkn[mt][1] = pk2(v[mt][2], v[mt][3]);
    }

    // redistribute P^T + PV MFMAs
    f32x4 oacc[2] = {{0.f,0.f,0.f,0.f},{0.f,0.f,0.f,0.f}};
#pragma unroll
    for (int ks = 0; ks < 2; ++ks) {
      const unsigned int p00 = (unsigned)__shfl((int)pkn[2*ks  ][0], srcA, 64);
      const unsigned int p10 = (unsigned)__shfl((int)pkn[2*ks+1][0], srcA, 64);
      const unsigned int p01 = (unsigned)__shfl((int)pkn[2*ks  ][1], srcA, 64);
      const unsigned int p11 = (unsigned)__shfl((int)pkn[2*ks+1][1], srcA, 64);
      const unsigned int q00 = (unsigned)__shfl((int)pkn[2*ks  ][0], srcB, 64);
      const unsigned int q10 = (unsigned)__shfl((int)pkn[2*ks+1][0], srcB, 64);
      const unsigned int q01 = (unsigned)__shfl((int)pkn[2*ks  ][1], srcB, 64);
      const unsigned int q11 = (unsigned)__shfl((int)pkn[2*ks+1][1], srcB, 64);
      B8 bf;
      bf.u[0] = gh ? p10 : p00;
      bf.u[1] = gh ? p11 : p01;
      bf.u[2] = gh ? q10 : q00;
      bf.u[3] = gh ? q11 : q01;
#pragma unroll
      for (int dt = 0; dt < 2; ++dt)
        oacc[dt] = __builtin_amdgcn_mfma_f32_16x16x32_bf16(va[dt][ks], bf.v, oacc[dt], 0, 0, 0);
    }

    // deferred normalization: O = inv * (P_raw . V); lane's j16 == q on both sides
    const int to = nt * 16 + j16;
    const int sw = (to & 7) << 5;
#pragma unroll
    for (int dt = 0; dt < 2; ++dt) {
      const int ch0 = wv * 32 + dt * 16 + g * 4;
      const uint2 w2 = make_uint2(pk2(oacc[dt][0] * inv, oacc[dt][1] * inv),
                                  pk2(oacc[dt][2] * inv, oacc[dt][3] * inv));
      *(uint2*)(Ob + to * 256 + ((ch0 * 2) ^ sw)) = w2;
    }
  }
  __syncthreads();

  // ---------------- Phase 4: out = O @ wp^T + b ----------------
  {
    const char* Ob2 = smem + KO_BASE;
    bf16x8 oa[4][4];
#pragma unroll
    for (int mt = 0; mt < 4; ++mt) {
      const int t = mt * 16 + j16;
      const int sw = (t & 7) << 5;
#pragma unroll
      for (int kt = 0; kt < 4; ++kt)
        oa[mt][kt] = *(const bf16x8*)(Ob2 + t * 256 + ((kt * 64 + g * 16) ^ sw));
    }
    float* ob = out + (size_t)bw * (T49 * CDIM);
#pragma unroll
    for (int ntl = 0; ntl < 2; ++ntl) {
      const int c = (wv * 2 + ntl) * 16 + j16;
      bf16x8 bfr[4];
#pragma unroll
      for (int kt = 0; kt < 4; ++kt)
        bfr[kt] = *(const bf16x8*)(wp + c * CDIM + kt * 32 + g * 8);
      const float bias = b_proj[c];
#pragma unroll
      for (int mt = 0; mt < 4; ++mt) {
        f32x4 acc = {0.f, 0.f, 0.f, 0.f};
#pragma unroll
        for (int kt = 0; kt < 4; ++kt)
          acc = __builtin_amdgcn_mfma_f32_16x16x32_bf16(oa[mt][kt], bfr[kt], acc, 0, 0, 0);
#pragma unroll
        for (int r = 0; r < 4; ++r) {
          const int t = mt * 16 + g * 4 + r;
          if (t < T49) ob[t * CDIM + c] = acc[r] + bias;
        }
      }
    }
  }
}

extern "C" void kernel_launch(void* const* d_in, const int* in_sizes, int n_in,
                              void* d_out, int out_size, void* d_ws, size_t ws_size,
                              hipStream_t stream) {
  const float* x      = (const float*)d_in[0];
  const float* mask   = (const float*)d_in[1];
  const float* w_qkv  = (const float*)d_in[2];
  const float* b_qkv  = (const float*)d_in[3];
  const float* w_proj = (const float*)d_in[4];
  const float* b_proj = (const float*)d_in[5];
  float* out = (float*)d_out;

  float* maskp = (float*)d_ws;                       // 64*64*64 f32 = 1 MB
  short* wq_bf = (short*)((char*)d_ws + 64*64*64*4); // 96 KB
  short* wp_bf = wq_bf + 3 * CDIM * CDIM;            // 32 KB

  hipLaunchKernelGGL(prep_kernel, dim3(1024), dim3(256), 0, stream,
                     w_qkv, w_proj, mask, wq_bf, wp_bf, maskp);
  hipLaunchKernelGGL(winattn_kernel, dim3(8192), dim3(256), 0, stream,
                     x, maskp, b_qkv, b_proj, wq_bf, wp_bf, out);
}